// Round 9
// baseline (271.277 us; speedup 1.0000x reference)
//
#include <hip/hip_runtime.h>
#include <hip/hip_bf16.h>

// ---------------------------------------------------------------------------
// 2-layer GAT on MI355X (gfx950).
//   CSR-by-dst: 8-way dst-partitioned (XCD-swizzled) histogram -> 2-stage
//   parallel scan -> partitioned cursor scatter. All atomics XCD-local
//   (cross-XCD cache-line ping-pong was the r5/r8 hidden cost).
//   gemm1: fp32 x -> in-register bf16 hi/lo split -> MFMA (2-term A-split);
//          epilogue writes Hb (bf16) AND alpha1 (fused att dot + quad-reduce).
//   agg1: softmax-aggregate -> bias+ReLU -> single bf16 out1 (layer-2 A).
//   gemm2: single-term bf16 A; epilogue fuses alpha2.
//   agg kernels: lane = (channel-group m16, edge-slot quad); one dwordx4
//   gather covers 4 edges; per-lane exp; quad-reduce once per node.
//   Softmax without segment-max (scale-invariant; exponents bounded ~|10|).
// ---------------------------------------------------------------------------

typedef __attribute__((ext_vector_type(8))) short bf16x8;
typedef __attribute__((ext_vector_type(4))) float f32x4;

#define LDS_STRIDE 136  // 128 + 8 pad (bf16): row stride 68 dwords -> 2-way max (free)
#define SCAT_CH 4096    // edges per partition-pass block (256 threads x 16)

__device__ inline unsigned short bf16bits(float v) {
    __hip_bfloat16 h = __float2bfloat16(v);
    return __builtin_bit_cast(unsigned short, h);
}
__device__ inline float bf16back(float v) {
    __hip_bfloat16 h = __float2bfloat16(v);
    return __bfloat162float(h);
}
// packed pair (lo 16 bits = elem0, hi = elem1) -> two fp32
__device__ inline float2 unpk(unsigned int u) {
    float2 r;
    r.x = __builtin_bit_cast(float, u << 16);
    r.y = __builtin_bit_cast(float, u & 0xffff0000u);
    return r;
}
__device__ inline unsigned int pk2(float a, float b) {
    return (unsigned int)bf16bits(a) | ((unsigned int)bf16bits(b) << 16);
}

// ---------------- CSR build ----------------

// 8-way dst-partitioned histogram: group g = blockIdx&7 counts only dsts in
// its contiguous 1/8 node range -> counter lines touched by ~one XCD.
__global__ __launch_bounds__(256) void hist_part(const int* __restrict__ ei,
                                                 int* __restrict__ counts, int E, int n) {
    int b = blockIdx.x;
    int part = b & 7;
    int base = (b >> 3) * SCAT_CH;
    int tot = E + n;
    int thr = (n + 7) >> 3;
    int lo = part * thr;
    int hi = lo + thr; if (hi > n) hi = n;
#pragma unroll
    for (int j = 0; j < SCAT_CH / 256; ++j) {
        int i = base + j * 256 + threadIdx.x;
        if (i >= tot) continue;
        int d = (i < E) ? ei[E + i] : (i - E);   // self-loops appended at end
        if (d < lo || d >= hi) continue;
        atomicAdd(&counts[d], 1);
    }
}

// stage 1: per-block (256-elem chunk) reduction -> bsum[b]
__global__ __launch_bounds__(256) void scan_partial(const int* __restrict__ counts,
                                                    int* __restrict__ bsum, int n) {
    int t = threadIdx.x;
    int i = blockIdx.x * 256 + t;
    int v = (i < n) ? counts[i] : 0;
    for (int off = 32; off; off >>= 1) v += __shfl_down(v, off, 64);
    __shared__ int ws[4];
    if ((t & 63) == 0) ws[t >> 6] = v;
    __syncthreads();
    if (t == 0) bsum[blockIdx.x] = ws[0] + ws[1] + ws[2] + ws[3];
}

// stage 2: each block replicates the exclusive scan of bsum (<=256 entries,
// L2-hot) then does its in-block exclusive scan; writes rowptr AND the
// scatter cursor (counts <- excl).
__global__ __launch_bounds__(256) void scan_final(int* __restrict__ counts,
                                                  const int* __restrict__ bsum,
                                                  int* __restrict__ rowptr,
                                                  int n, int tot, int nb) {
    int t = threadIdx.x;
    int lane = t & 63, w = t >> 6;
    __shared__ int sb[256];
    __shared__ int ws1[4], ws2[4];
    {   // replicated exclusive scan of block sums
        int orig = (t < nb) ? bsum[t] : 0;
        int v = orig;
        for (int off = 1; off < 64; off <<= 1) {
            int u = __shfl_up(v, off, 64);
            if (lane >= off) v += u;
        }
        if (lane == 63) ws1[w] = v;
        __syncthreads();
        int woff = 0;
        for (int k = 0; k < w; ++k) woff += ws1[k];
        sb[t] = woff + v - orig;
        __syncthreads();
    }
    int bpre = sb[blockIdx.x];
    int i = blockIdx.x * 256 + t;
    int orig = (i < n) ? counts[i] : 0;
    int v = orig;
    for (int off = 1; off < 64; off <<= 1) {
        int u = __shfl_up(v, off, 64);
        if (lane >= off) v += u;
    }
    if (lane == 63) ws2[w] = v;
    __syncthreads();
    int woff = 0;
    for (int k = 0; k < w; ++k) woff += ws2[k];
    int excl = bpre + woff + v - orig;
    if (i < n) {
        rowptr[i] = excl;
        counts[i] = excl;        // scatter cursor
    }
    if (blockIdx.x == 0 && t == 0) rowptr[n] = tot;
}

// partitioned cursor scatter: atomics + srcs writes stay within one
// partition (-> ~one XCD); correctness independent of actual XCD mapping.
__global__ __launch_bounds__(256) void scatter_part(const int* __restrict__ ei,
                                                    int* __restrict__ cursor,
                                                    int* __restrict__ srcs, int E, int n) {
    int b = blockIdx.x;
    int part = b & 7;
    int base = (b >> 3) * SCAT_CH;
    int tot = E + n;
    int thr = (n + 7) >> 3;
    int lo = part * thr;
    int hi = lo + thr; if (hi > n) hi = n;
#pragma unroll
    for (int j = 0; j < SCAT_CH / 256; ++j) {
        int i = base + j * 256 + threadIdx.x;
        if (i >= tot) continue;
        int d = (i < E) ? ei[E + i] : (i - E);
        if (d < lo || d >= hi) continue;
        int s = (i < E) ? ei[i] : d;
        int pos = atomicAdd(&cursor[d], 1);
        srcs[pos] = s;
    }
}

// ---------------- conversions ----------------

// both weights: W [128 K][128 N] fp32 -> Bt [128 N][128 K] bf16 (transpose+round)
__global__ __launch_bounds__(256) void convWt2_kernel(const float* __restrict__ W1,
                                                      const float* __restrict__ W2,
                                                      unsigned short* __restrict__ Bt1,
                                                      unsigned short* __restrict__ Bt2) {
    int i = blockIdx.x * 256 + threadIdx.x;   // 32768
    const float* W = (i < 16384) ? W1 : W2;
    unsigned short* Bt = (i < 16384) ? Bt1 : Bt2;
    int j = i & 16383;
    int k = j >> 7, n = j & 127;
    Bt[n * 128 + k] = bf16bits(W[j]);
}

// ---------------- GEMM layer 1: Hb = split(x) @ B1, alpha1 fused ----------------

__global__ __launch_bounds__(256) void gemm1_fused(const float* __restrict__ x,
                                                   const unsigned short* __restrict__ Bt,
                                                   unsigned short* __restrict__ Hb,
                                                   const float* __restrict__ a_src,
                                                   const float* __restrict__ a_dst,
                                                   float* __restrict__ asrc,
                                                   float* __restrict__ adst, int M) {
    __shared__ unsigned short Bs[128 * LDS_STRIDE];
    int t = threadIdx.x;
    for (int i = t; i < 128 * 16; i += 256) {
        int r = i >> 4, c = (i & 15) * 8;
        uint4 v = *reinterpret_cast<const uint4*>(Bt + r * 128 + c);
        *reinterpret_cast<uint4*>(&Bs[r * LDS_STRIDE + c]) = v;
    }
    __syncthreads();

    int wave = t >> 6, lane = t & 63;
    int m16 = lane & 15, quad = lane >> 4;
    int row0 = blockIdx.x * 64 + wave * 16;
    int arow = row0 + m16;
    if (arow > M - 1) arow = M - 1;           // clamp loads; stores predicated

    f32x4 acc[8] = {};
#pragma unroll
    for (int ks = 0; ks < 4; ++ks) {
        int k0 = ks * 32 + quad * 8;
        float4 v0 = *reinterpret_cast<const float4*>(x + (size_t)arow * 128 + k0);
        float4 v1 = *reinterpret_cast<const float4*>(x + (size_t)arow * 128 + k0 + 4);
        float vv[8] = {v0.x, v0.y, v0.z, v0.w, v1.x, v1.y, v1.z, v1.w};
        union { unsigned short u[8]; bf16x8 v; } ahi, alo;
#pragma unroll
        for (int j = 0; j < 8; ++j) {
            ahi.u[j] = bf16bits(vv[j]);
            alo.u[j] = bf16bits(vv[j] - bf16back(vv[j]));
        }
#pragma unroll
        for (int nt = 0; nt < 8; ++nt) {
            bf16x8 b = __builtin_bit_cast(bf16x8,
                *reinterpret_cast<const uint4*>(&Bs[(nt * 16 + m16) * LDS_STRIDE + k0]));
            acc[nt] = __builtin_amdgcn_mfma_f32_16x16x32_bf16(alo.v, b, acc[nt], 0, 0, 0);
            acc[nt] = __builtin_amdgcn_mfma_f32_16x16x32_bf16(ahi.v, b, acc[nt], 0, 0, 0);
        }
    }
    // C/D layout: col = lane&15, row = quad*4 + reg   [m89-verified]
#pragma unroll
    for (int nt = 0; nt < 8; ++nt) {
#pragma unroll
        for (int r = 0; r < 4; ++r) {
            int gr = row0 + quad * 4 + r;
            if (gr < M) Hb[(size_t)gr * 128 + nt * 16 + m16] = bf16bits(acc[nt][r]);
        }
    }
    // fused alpha1: per (row, head) dot over 128 cols; lane holds cols nt*16+m16
    float asa[4], asb[4], ada[4], adb[4];
#pragma unroll
    for (int h = 0; h < 4; ++h) {
        asa[h] = a_src[h * 32 + m16];
        asb[h] = a_src[h * 32 + 16 + m16];
        ada[h] = a_dst[h * 32 + m16];
        adb[h] = a_dst[h * 32 + 16 + m16];
    }
#pragma unroll
    for (int r = 0; r < 4; ++r) {
        int gr = row0 + quad * 4 + r;
        float ps[4], pd[4];
#pragma unroll
        for (int h = 0; h < 4; ++h) {
            ps[h] = acc[2 * h][r] * asa[h] + acc[2 * h + 1][r] * asb[h];
            pd[h] = acc[2 * h][r] * ada[h] + acc[2 * h + 1][r] * adb[h];
        }
#pragma unroll
        for (int off = 1; off < 16; off <<= 1) {
#pragma unroll
            for (int h = 0; h < 4; ++h) {
                ps[h] += __shfl_xor(ps[h], off, 64);
                pd[h] += __shfl_xor(pd[h], off, 64);
            }
        }
        if (m16 == 0 && gr < M) {
#pragma unroll
            for (int h = 0; h < 4; ++h) {
                asrc[gr * 4 + h] = ps[h];
                adst[gr * 4 + h] = pd[h];
            }
        }
    }
}

// ---------------- GEMM layer 2: Hb = A1 @ B2 (single-term bf16), alpha2 fused ----

__global__ __launch_bounds__(256) void gemm2_fused(const unsigned short* __restrict__ A1,
                                                   const unsigned short* __restrict__ Bt,
                                                   unsigned short* __restrict__ Hb,
                                                   const float* __restrict__ a_src,
                                                   const float* __restrict__ a_dst,
                                                   float* __restrict__ asrc,
                                                   float* __restrict__ adst, int M) {
    __shared__ unsigned short Bs[128 * LDS_STRIDE];
    int t = threadIdx.x;
    for (int i = t; i < 128 * 16; i += 256) {
        int r = i >> 4, c = (i & 15) * 8;
        uint4 v = *reinterpret_cast<const uint4*>(Bt + r * 128 + c);
        *reinterpret_cast<uint4*>(&Bs[r * LDS_STRIDE + c]) = v;
    }
    __syncthreads();

    int wave = t >> 6, lane = t & 63;
    int m16 = lane & 15, quad = lane >> 4;
    int row0 = blockIdx.x * 64 + wave * 16;
    int arow = row0 + m16;
    if (arow > M - 1) arow = M - 1;

    f32x4 acc[8] = {};
#pragma unroll
    for (int ks = 0; ks < 4; ++ks) {
        int k0 = ks * 32 + quad * 8;
        bf16x8 a = __builtin_bit_cast(bf16x8,
            *reinterpret_cast<const uint4*>(A1 + (size_t)arow * 128 + k0));
#pragma unroll
        for (int nt = 0; nt < 8; ++nt) {
            bf16x8 b = __builtin_bit_cast(bf16x8,
                *reinterpret_cast<const uint4*>(&Bs[(nt * 16 + m16) * LDS_STRIDE + k0]));
            acc[nt] = __builtin_amdgcn_mfma_f32_16x16x32_bf16(a, b, acc[nt], 0, 0, 0);
        }
    }
#pragma unroll
    for (int nt = 0; nt < 8; ++nt) {
#pragma unroll
        for (int r = 0; r < 4; ++r) {
            int gr = row0 + quad * 4 + r;
            if (gr < M) Hb[(size_t)gr * 128 + nt * 16 + m16] = bf16bits(acc[nt][r]);
        }
    }
    // fused alpha2: single head over 128 cols
    float as2[8], ad2[8];
#pragma unroll
    for (int nt = 0; nt < 8; ++nt) {
        as2[nt] = a_src[nt * 16 + m16];
        ad2[nt] = a_dst[nt * 16 + m16];
    }
#pragma unroll
    for (int r = 0; r < 4; ++r) {
        int gr = row0 + quad * 4 + r;
        float ps = 0.f, pd = 0.f;
#pragma unroll
        for (int nt = 0; nt < 8; ++nt) {
            ps += acc[nt][r] * as2[nt];
            pd += acc[nt][r] * ad2[nt];
        }
#pragma unroll
        for (int off = 1; off < 16; off <<= 1) {
            ps += __shfl_xor(ps, off, 64);
            pd += __shfl_xor(pd, off, 64);
        }
        if (m16 == 0 && gr < M) {
            asrc[gr] = ps;
            adst[gr] = pd;
        }
    }
}

// ---------------- aggregation ----------------
// Lane decomposition: m16 = lane&15 -> 8-channel group (16 B of the 256 B
// row); quad = lane>>4 -> edge slot. One dwordx4 gather covers 4 edges.
// Per-lane exp (no per-edge shfl); den/acc quad-reduced once per node.

// layer-1: 4 heads x 32 ch; head of channel-group = m16>>2.
// fused bias+ReLU; writes layer-2 input as single bf16 (precision budget).
__global__ __launch_bounds__(256) void agg1_kernel(const unsigned short* __restrict__ Hb,
                                                   const float* __restrict__ asrc,
                                                   const float* __restrict__ adst,
                                                   const int* __restrict__ rowptr,
                                                   const int* __restrict__ srcs,
                                                   const float* __restrict__ bias,
                                                   unsigned short* __restrict__ o1, int n) {
    int wid = (blockIdx.x * 256 + threadIdx.x) >> 6;
    int lane = threadIdx.x & 63;
    if (wid >= n) return;
    int m16 = lane & 15, quad = lane >> 4;
    int hd = m16 >> 2;
    int d = wid;
    int beg = rowptr[d], end = rowptr[d + 1];
    float adh = adst[d * 4 + hd];
    const uint4* H4 = reinterpret_cast<const uint4*>(Hb);
    float acc[8] = {};
    float den = 0.f;

    auto body = [&](int p, bool chk) {
        int ep = p + quad;
        bool valid = !chk || (ep < end);
        int se = srcs[valid ? ep : beg];
        float e = asrc[se * 4 + hd] + adh;
        e = (e > 0.f) ? e : 0.2f * e;          // leaky_relu
        float pv = __expf(e);
        if (!valid) pv = 0.f;
        den += pv;
        uint4 hv = H4[(size_t)se * 16 + m16];
        float2 f0 = unpk(hv.x), f1 = unpk(hv.y), f2 = unpk(hv.z), f3 = unpk(hv.w);
        acc[0] += pv * f0.x; acc[1] += pv * f0.y;
        acc[2] += pv * f1.x; acc[3] += pv * f1.y;
        acc[4] += pv * f2.x; acc[5] += pv * f2.y;
        acc[6] += pv * f3.x; acc[7] += pv * f3.y;
    };
    int p = beg;
    for (; p + 8 <= end; p += 8) { body(p, false); body(p + 4, false); }
    for (; p < end; p += 4) body(p, true);

#pragma unroll
    for (int off = 16; off < 64; off <<= 1) {
        den += __shfl_xor(den, off, 64);
#pragma unroll
        for (int j = 0; j < 8; ++j) acc[j] += __shfl_xor(acc[j], off, 64);
    }
    if (quad == 0) {
        float inv = 1.f / den;
        const float4* bv4 = reinterpret_cast<const float4*>(bias);
        float4 b0 = bv4[m16 * 2], b1 = bv4[m16 * 2 + 1];
        uint4 hw;
        hw.x = pk2(fmaxf(b0.x + acc[0] * inv, 0.f), fmaxf(b0.y + acc[1] * inv, 0.f));
        hw.y = pk2(fmaxf(b0.z + acc[2] * inv, 0.f), fmaxf(b0.w + acc[3] * inv, 0.f));
        hw.z = pk2(fmaxf(b1.x + acc[4] * inv, 0.f), fmaxf(b1.y + acc[5] * inv, 0.f));
        hw.w = pk2(fmaxf(b1.z + acc[6] * inv, 0.f), fmaxf(b1.w + acc[7] * inv, 0.f));
        *reinterpret_cast<uint4*>(o1 + (size_t)d * 128 + m16 * 8) = hw;
    }
}

// layer-2: 1 head x 128 ch; + b2, no ReLU; fp32 output.
__global__ __launch_bounds__(256) void agg2_kernel(const unsigned short* __restrict__ Hb,
                                                   const float* __restrict__ asrc,
                                                   const float* __restrict__ adst,
                                                   const int* __restrict__ rowptr,
                                                   const int* __restrict__ srcs,
                                                   const float* __restrict__ bias,
                                                   float* __restrict__ out, int n) {
    int wid = (blockIdx.x * 256 + threadIdx.x) >> 6;
    int lane = threadIdx.x & 63;
    if (wid >= n) return;
    int m16 = lane & 15, quad = lane >> 4;
    int d = wid;
    int beg = rowptr[d], end = rowptr[d + 1];
    float ad = adst[d];
    const uint4* H4 = reinterpret_cast<const uint4*>(Hb);
    float acc[8] = {};
    float den = 0.f;

    auto body = [&](int p, bool chk) {
        int ep = p + quad;
        bool valid = !chk || (ep < end);
        int se = srcs[valid ? ep : beg];
        float e = asrc[se] + ad;
        e = (e > 0.f) ? e : 0.2f * e;
        float pv = __expf(e);
        if (!valid) pv = 0.f;
        den += pv;
        uint4 hv = H4[(size_t)se * 16 + m16];
        float2 f0 = unpk(hv.x), f1 = unpk(hv.y), f2 = unpk(hv.z), f3 = unpk(hv.w);
        acc[0] += pv * f0.x; acc[1] += pv * f0.y;
        acc[2] += pv * f1.x; acc[3] += pv * f1.y;
        acc[4] += pv * f2.x; acc[5] += pv * f2.y;
        acc[6] += pv * f3.x; acc[7] += pv * f3.y;
    };
    int p = beg;
    for (; p + 8 <= end; p += 8) { body(p, false); body(p + 4, false); }
    for (; p < end; p += 4) body(p, true);

#pragma unroll
    for (int off = 16; off < 64; off <<= 1) {
        den += __shfl_xor(den, off, 64);
#pragma unroll
        for (int j = 0; j < 8; ++j) acc[j] += __shfl_xor(acc[j], off, 64);
    }
    float inv = 1.f / den;
    const float4* bv4 = reinterpret_cast<const float4*>(bias);
    float4 b0 = bv4[m16 * 2], b1 = bv4[m16 * 2 + 1];
    if (quad == 0) {
        float4 o;
        o.x = b0.x + acc[0] * inv; o.y = b0.y + acc[1] * inv;
        o.z = b0.z + acc[2] * inv; o.w = b0.w + acc[3] * inv;
        *reinterpret_cast<float4*>(out + (size_t)d * 128 + m16 * 8) = o;
    }
    if (quad == 1) {
        float4 o;
        o.x = b1.x + acc[4] * inv; o.y = b1.y + acc[5] * inv;
        o.z = b1.z + acc[6] * inv; o.w = b1.w + acc[7] * inv;
        *reinterpret_cast<float4*>(out + (size_t)d * 128 + m16 * 8 + 4) = o;
    }
}

// ---------------- launch ----------------

extern "C" void kernel_launch(void* const* d_in, const int* in_sizes, int n_in,
                              void* d_out, int out_size, void* d_ws, size_t ws_size,
                              hipStream_t stream) {
    const float* x   = (const float*)d_in[0];
    const int*   ei  = (const int*)d_in[1];
    const float* W1  = (const float*)d_in[2];
    const float* as1 = (const float*)d_in[3];
    const float* ad1 = (const float*)d_in[4];
    const float* b1  = (const float*)d_in[5];
    const float* W2  = (const float*)d_in[6];
    const float* as2 = (const float*)d_in[7];
    const float* ad2 = (const float*)d_in[8];
    const float* b2  = (const float*)d_in[9];

    int N = in_sizes[0] / 128;
    int E = in_sizes[1] / 2;
    int tot = E + N;
    int nb = (N + 255) / 256;           // scan blocks (<=256 required; N=50k -> 196)
    int nscat = (tot + SCAT_CH - 1) / SCAT_CH;

    char* wsb = (char*)d_ws;
    size_t off = 0;
    auto alloc = [&](size_t bytes) {
        void* p = wsb + off;
        off += (bytes + 255) & ~(size_t)255;
        return p;
    };
    unsigned short* A1  = (unsigned short*)alloc((size_t)N * 128 * 2); // out1 bf16 (agg1->gemm2)
    unsigned short* Hb  = (unsigned short*)alloc((size_t)N * 128 * 2); // h bf16 (h1 then h2)
    unsigned short* Bt1 = (unsigned short*)alloc(128 * 128 * 2);
    unsigned short* Bt2 = (unsigned short*)alloc(128 * 128 * 2);
    int*   counts = (int*)alloc((size_t)N * 4);
    int*   rowptr = (int*)alloc((size_t)(N + 1) * 4);
    int*   srcs   = (int*)alloc((size_t)tot * 4);
    int*   bsum   = (int*)alloc(256 * 4);
    float* asrc1  = (float*)alloc((size_t)N * 4 * 4);
    float* adst1  = (float*)alloc((size_t)N * 4 * 4);
    float* asrc2  = (float*)alloc((size_t)N * 4);
    float* adst2  = (float*)alloc((size_t)N * 4);
    (void)ws_size; (void)n_in; (void)out_size;

    // CSR by dst (shared by both layers) — all atomics XCD-local
    hipMemsetAsync(counts, 0, (size_t)N * 4, stream);
    hist_part<<<nscat * 8, 256, 0, stream>>>(ei, counts, E, N);
    scan_partial<<<nb, 256, 0, stream>>>(counts, bsum, N);
    scan_final<<<nb, 256, 0, stream>>>(counts, bsum, rowptr, N, tot, nb);
    scatter_part<<<nscat * 8, 256, 0, stream>>>(ei, counts, srcs, E, N);

    // weight conversions (both in one launch)
    convWt2_kernel<<<128, 256, 0, stream>>>(W1, W2, Bt1, Bt2);

    int gblocks = (N + 63) / 64;

    // layer 1 (x split fused into GEMM; alpha1 fused into epilogue)
    gemm1_fused<<<gblocks, 256, 0, stream>>>(x, Bt1, Hb, as1, ad1, asrc1, adst1, N);
    agg1_kernel<<<(N + 3) / 4, 256, 0, stream>>>(Hb, asrc1, adst1, rowptr, srcs, b1, A1, N);

    // layer 2 (single-term bf16 A; alpha2 fused into epilogue)
    gemm2_fused<<<gblocks, 256, 0, stream>>>(A1, Bt2, Hb, as2, ad2, asrc2, adst2, N);
    agg2_kernel<<<(N + 3) / 4, 256, 0, stream>>>(Hb, asrc2, adst2, rowptr, srcs, b2,
                                                 (float*)d_out, N);
}

// Round 10
// 250.728 us; speedup vs baseline: 1.0820x; 1.0820x over previous
//
#include <hip/hip_runtime.h>
#include <hip/hip_bf16.h>

// ---------------------------------------------------------------------------
// 2-layer GAT on MI355X (gfx950).  [r8 revert — r9's CSR restructure regressed]
//   CSR-by-dst: hist+rank (one atomic pass; atomic's return value is the
//   free per-edge rank) / 3-stage parallel scan / atomic-free
//   dst-partitioned scatter (8-way XCD swizzle).
//   gemm1: fp32 x -> in-register bf16 hi/lo split -> MFMA (2-term A-split);
//          epilogue writes Hb (bf16) AND alpha1 (fused att dot + quad-reduce).
//   agg1: softmax-aggregate -> bias+ReLU -> single bf16 out1 (layer-2 A).
//   gemm2: single-term bf16 A (precision budget: absmax headroom 4.5x);
//          epilogue fuses alpha2.
//   agg kernels: lane = (channel-group m16, edge-slot quad); one dwordx4
//   gather covers 4 edges; per-lane exp; quad-reduce once per node.
//   Softmax without segment-max (scale-invariant; exponents bounded ~|10|).
// ---------------------------------------------------------------------------

typedef __attribute__((ext_vector_type(8))) short bf16x8;
typedef __attribute__((ext_vector_type(4))) float f32x4;

#define LDS_STRIDE 136  // 128 + 8 pad (bf16): row stride 68 dwords -> 2-way max (free)
#define SCAT_CH 4096    // edges per scatter block (256 threads x 16)

__device__ inline unsigned short bf16bits(float v) {
    __hip_bfloat16 h = __float2bfloat16(v);
    return __builtin_bit_cast(unsigned short, h);
}
__device__ inline float bf16back(float v) {
    __hip_bfloat16 h = __float2bfloat16(v);
    return __bfloat162float(h);
}
// packed pair (lo 16 bits = elem0, hi = elem1) -> two fp32
__device__ inline float2 unpk(unsigned int u) {
    float2 r;
    r.x = __builtin_bit_cast(float, u << 16);
    r.y = __builtin_bit_cast(float, u & 0xffff0000u);
    return r;
}
__device__ inline unsigned int pk2(float a, float b) {
    return (unsigned int)bf16bits(a) | ((unsigned int)bf16bits(b) << 16);
}

// ---------------- CSR build ----------------

__global__ __launch_bounds__(256) void hist_rank(const int* __restrict__ ei,
                                                 int* __restrict__ counts,
                                                 int* __restrict__ rank, int E, int n) {
    int i = blockIdx.x * 256 + threadIdx.x;
    int tot = E + n;
    if (i >= tot) return;
    int d = (i < E) ? ei[E + i] : (i - E);   // self-loops appended at the end
    int r = atomicAdd(&counts[d], 1);
    rank[i] = r;
}

__global__ __launch_bounds__(256) void scan_partial(const int* __restrict__ counts,
                                                    int* __restrict__ bsum, int n) {
    int t = threadIdx.x;
    int i = blockIdx.x * 256 + t;
    int v = (i < n) ? counts[i] : 0;
    for (int off = 32; off; off >>= 1) v += __shfl_down(v, off, 64);
    __shared__ int ws[4];
    if ((t & 63) == 0) ws[t >> 6] = v;
    __syncthreads();
    if (t == 0) bsum[blockIdx.x] = ws[0] + ws[1] + ws[2] + ws[3];
}

__global__ __launch_bounds__(256) void scan_bsums(int* __restrict__ bsum, int nb) {
    int t = threadIdx.x;
    int lane = t & 63, w = t >> 6;
    int orig = (t < nb) ? bsum[t] : 0;
    int v = orig;
    for (int off = 1; off < 64; off <<= 1) {
        int u = __shfl_up(v, off, 64);
        if (lane >= off) v += u;
    }
    __shared__ int ws[4];
    if (lane == 63) ws[w] = v;
    __syncthreads();
    int woff = 0;
    for (int i = 0; i < w; ++i) woff += ws[i];
    if (t < nb) bsum[t] = woff + v - orig;   // exclusive
}

__global__ __launch_bounds__(256) void scan_final(const int* __restrict__ counts,
                                                  const int* __restrict__ bsum,
                                                  int* __restrict__ rowptr, int n, int tot) {
    int t = threadIdx.x;
    int i = blockIdx.x * 256 + t;
    int lane = t & 63, w = t >> 6;
    int orig = (i < n) ? counts[i] : 0;
    int v = orig;
    for (int off = 1; off < 64; off <<= 1) {
        int u = __shfl_up(v, off, 64);
        if (lane >= off) v += u;
    }
    __shared__ int ws[4];
    if (lane == 63) ws[w] = v;
    __syncthreads();
    int woff = 0;
    for (int k = 0; k < w; ++k) woff += ws[k];
    int excl = bsum[blockIdx.x] + woff + v - orig;
    if (i < n) rowptr[i] = excl;
    if (blockIdx.x == 0 && t == 0) rowptr[n] = tot;
}

// atomic-free scatter, dst-partitioned into 8 groups (XCD swizzle: blockIdx&7)
__global__ __launch_bounds__(256) void scatter_part(const int* __restrict__ ei,
                                                    const int* __restrict__ rowptr,
                                                    const int* __restrict__ rank,
                                                    int* __restrict__ srcs, int E, int n) {
    int b = blockIdx.x;
    int part = b & 7;
    int base = (b >> 3) * SCAT_CH;
    int tot = E + n;
    int thr = (n + 7) >> 3;
    int lo = part * thr;
    int hi = lo + thr; if (hi > n) hi = n;
#pragma unroll
    for (int j = 0; j < SCAT_CH / 256; ++j) {
        int i = base + j * 256 + threadIdx.x;
        if (i >= tot) continue;
        int d = (i < E) ? ei[E + i] : (i - E);
        if (d < lo || d >= hi) continue;
        int s = (i < E) ? ei[i] : d;
        srcs[rowptr[d] + rank[i]] = s;
    }
}

// ---------------- conversions ----------------

// both weights: W [128 K][128 N] fp32 -> Bt [128 N][128 K] bf16 (transpose+round)
__global__ __launch_bounds__(256) void convWt2_kernel(const float* __restrict__ W1,
                                                      const float* __restrict__ W2,
                                                      unsigned short* __restrict__ Bt1,
                                                      unsigned short* __restrict__ Bt2) {
    int i = blockIdx.x * 256 + threadIdx.x;   // 32768
    const float* W = (i < 16384) ? W1 : W2;
    unsigned short* Bt = (i < 16384) ? Bt1 : Bt2;
    int j = i & 16383;
    int k = j >> 7, n = j & 127;
    Bt[n * 128 + k] = bf16bits(W[j]);
}

// ---------------- GEMM layer 1: Hb = split(x) @ B1, alpha1 fused ----------------

__global__ __launch_bounds__(256) void gemm1_fused(const float* __restrict__ x,
                                                   const unsigned short* __restrict__ Bt,
                                                   unsigned short* __restrict__ Hb,
                                                   const float* __restrict__ a_src,
                                                   const float* __restrict__ a_dst,
                                                   float* __restrict__ asrc,
                                                   float* __restrict__ adst, int M) {
    __shared__ unsigned short Bs[128 * LDS_STRIDE];
    int t = threadIdx.x;
    for (int i = t; i < 128 * 16; i += 256) {
        int r = i >> 4, c = (i & 15) * 8;
        uint4 v = *reinterpret_cast<const uint4*>(Bt + r * 128 + c);
        *reinterpret_cast<uint4*>(&Bs[r * LDS_STRIDE + c]) = v;
    }
    __syncthreads();

    int wave = t >> 6, lane = t & 63;
    int m16 = lane & 15, quad = lane >> 4;
    int row0 = blockIdx.x * 64 + wave * 16;
    int arow = row0 + m16;
    if (arow > M - 1) arow = M - 1;           // clamp loads; stores predicated

    f32x4 acc[8] = {};
#pragma unroll
    for (int ks = 0; ks < 4; ++ks) {
        int k0 = ks * 32 + quad * 8;
        float4 v0 = *reinterpret_cast<const float4*>(x + (size_t)arow * 128 + k0);
        float4 v1 = *reinterpret_cast<const float4*>(x + (size_t)arow * 128 + k0 + 4);
        float vv[8] = {v0.x, v0.y, v0.z, v0.w, v1.x, v1.y, v1.z, v1.w};
        union { unsigned short u[8]; bf16x8 v; } ahi, alo;
#pragma unroll
        for (int j = 0; j < 8; ++j) {
            ahi.u[j] = bf16bits(vv[j]);
            alo.u[j] = bf16bits(vv[j] - bf16back(vv[j]));
        }
#pragma unroll
        for (int nt = 0; nt < 8; ++nt) {
            bf16x8 b = __builtin_bit_cast(bf16x8,
                *reinterpret_cast<const uint4*>(&Bs[(nt * 16 + m16) * LDS_STRIDE + k0]));
            acc[nt] = __builtin_amdgcn_mfma_f32_16x16x32_bf16(alo.v, b, acc[nt], 0, 0, 0);
            acc[nt] = __builtin_amdgcn_mfma_f32_16x16x32_bf16(ahi.v, b, acc[nt], 0, 0, 0);
        }
    }
    // C/D layout: col = lane&15, row = quad*4 + reg   [m89-verified]
#pragma unroll
    for (int nt = 0; nt < 8; ++nt) {
#pragma unroll
        for (int r = 0; r < 4; ++r) {
            int gr = row0 + quad * 4 + r;
            if (gr < M) Hb[(size_t)gr * 128 + nt * 16 + m16] = bf16bits(acc[nt][r]);
        }
    }
    // fused alpha1: per (row, head) dot over 128 cols; lane holds cols nt*16+m16
    float asa[4], asb[4], ada[4], adb[4];
#pragma unroll
    for (int h = 0; h < 4; ++h) {
        asa[h] = a_src[h * 32 + m16];
        asb[h] = a_src[h * 32 + 16 + m16];
        ada[h] = a_dst[h * 32 + m16];
        adb[h] = a_dst[h * 32 + 16 + m16];
    }
#pragma unroll
    for (int r = 0; r < 4; ++r) {
        int gr = row0 + quad * 4 + r;
        float ps[4], pd[4];
#pragma unroll
        for (int h = 0; h < 4; ++h) {
            ps[h] = acc[2 * h][r] * asa[h] + acc[2 * h + 1][r] * asb[h];
            pd[h] = acc[2 * h][r] * ada[h] + acc[2 * h + 1][r] * adb[h];
        }
#pragma unroll
        for (int off = 1; off < 16; off <<= 1) {
#pragma unroll
            for (int h = 0; h < 4; ++h) {
                ps[h] += __shfl_xor(ps[h], off, 64);
                pd[h] += __shfl_xor(pd[h], off, 64);
            }
        }
        if (m16 == 0 && gr < M) {
#pragma unroll
            for (int h = 0; h < 4; ++h) {
                asrc[gr * 4 + h] = ps[h];
                adst[gr * 4 + h] = pd[h];
            }
        }
    }
}

// ---------------- GEMM layer 2: Hb = A1 @ B2 (single-term bf16), alpha2 fused ----

__global__ __launch_bounds__(256) void gemm2_fused(const unsigned short* __restrict__ A1,
                                                   const unsigned short* __restrict__ Bt,
                                                   unsigned short* __restrict__ Hb,
                                                   const float* __restrict__ a_src,
                                                   const float* __restrict__ a_dst,
                                                   float* __restrict__ asrc,
                                                   float* __restrict__ adst, int M) {
    __shared__ unsigned short Bs[128 * LDS_STRIDE];
    int t = threadIdx.x;
    for (int i = t; i < 128 * 16; i += 256) {
        int r = i >> 4, c = (i & 15) * 8;
        uint4 v = *reinterpret_cast<const uint4*>(Bt + r * 128 + c);
        *reinterpret_cast<uint4*>(&Bs[r * LDS_STRIDE + c]) = v;
    }
    __syncthreads();

    int wave = t >> 6, lane = t & 63;
    int m16 = lane & 15, quad = lane >> 4;
    int row0 = blockIdx.x * 64 + wave * 16;
    int arow = row0 + m16;
    if (arow > M - 1) arow = M - 1;

    f32x4 acc[8] = {};
#pragma unroll
    for (int ks = 0; ks < 4; ++ks) {
        int k0 = ks * 32 + quad * 8;
        bf16x8 a = __builtin_bit_cast(bf16x8,
            *reinterpret_cast<const uint4*>(A1 + (size_t)arow * 128 + k0));
#pragma unroll
        for (int nt = 0; nt < 8; ++nt) {
            bf16x8 b = __builtin_bit_cast(bf16x8,
                *reinterpret_cast<const uint4*>(&Bs[(nt * 16 + m16) * LDS_STRIDE + k0]));
            acc[nt] = __builtin_amdgcn_mfma_f32_16x16x32_bf16(a, b, acc[nt], 0, 0, 0);
        }
    }
#pragma unroll
    for (int nt = 0; nt < 8; ++nt) {
#pragma unroll
        for (int r = 0; r < 4; ++r) {
            int gr = row0 + quad * 4 + r;
            if (gr < M) Hb[(size_t)gr * 128 + nt * 16 + m16] = bf16bits(acc[nt][r]);
        }
    }
    // fused alpha2: single head over 128 cols
    float as2[8], ad2[8];
#pragma unroll
    for (int nt = 0; nt < 8; ++nt) {
        as2[nt] = a_src[nt * 16 + m16];
        ad2[nt] = a_dst[nt * 16 + m16];
    }
#pragma unroll
    for (int r = 0; r < 4; ++r) {
        int gr = row0 + quad * 4 + r;
        float ps = 0.f, pd = 0.f;
#pragma unroll
        for (int nt = 0; nt < 8; ++nt) {
            ps += acc[nt][r] * as2[nt];
            pd += acc[nt][r] * ad2[nt];
        }
#pragma unroll
        for (int off = 1; off < 16; off <<= 1) {
            ps += __shfl_xor(ps, off, 64);
            pd += __shfl_xor(pd, off, 64);
        }
        if (m16 == 0 && gr < M) {
            asrc[gr] = ps;
            adst[gr] = pd;
        }
    }
}

// ---------------- aggregation ----------------
// Lane decomposition: m16 = lane&15 -> 8-channel group (16 B of the 256 B
// row); quad = lane>>4 -> edge slot. One dwordx4 gather covers 4 edges.
// Per-lane exp (no per-edge shfl); den/acc quad-reduced once per node.

// layer-1: 4 heads x 32 ch; head of channel-group = m16>>2.
// fused bias+ReLU; writes layer-2 input as single bf16 (precision budget).
__global__ __launch_bounds__(256) void agg1_kernel(const unsigned short* __restrict__ Hb,
                                                   const float* __restrict__ asrc,
                                                   const float* __restrict__ adst,
                                                   const int* __restrict__ rowptr,
                                                   const int* __restrict__ srcs,
                                                   const float* __restrict__ bias,
                                                   unsigned short* __restrict__ o1, int n) {
    int wid = (blockIdx.x * 256 + threadIdx.x) >> 6;
    int lane = threadIdx.x & 63;
    if (wid >= n) return;
    int m16 = lane & 15, quad = lane >> 4;
    int hd = m16 >> 2;
    int d = wid;
    int beg = rowptr[d], end = rowptr[d + 1];
    float adh = adst[d * 4 + hd];
    const uint4* H4 = reinterpret_cast<const uint4*>(Hb);
    float acc[8] = {};
    float den = 0.f;

    auto body = [&](int p, bool chk) {
        int ep = p + quad;
        bool valid = !chk || (ep < end);
        int se = srcs[valid ? ep : beg];
        float e = asrc[se * 4 + hd] + adh;
        e = (e > 0.f) ? e : 0.2f * e;          // leaky_relu
        float pv = __expf(e);
        if (!valid) pv = 0.f;
        den += pv;
        uint4 hv = H4[(size_t)se * 16 + m16];
        float2 f0 = unpk(hv.x), f1 = unpk(hv.y), f2 = unpk(hv.z), f3 = unpk(hv.w);
        acc[0] += pv * f0.x; acc[1] += pv * f0.y;
        acc[2] += pv * f1.x; acc[3] += pv * f1.y;
        acc[4] += pv * f2.x; acc[5] += pv * f2.y;
        acc[6] += pv * f3.x; acc[7] += pv * f3.y;
    };
    int p = beg;
    for (; p + 8 <= end; p += 8) { body(p, false); body(p + 4, false); }
    for (; p < end; p += 4) body(p, true);

#pragma unroll
    for (int off = 16; off < 64; off <<= 1) {
        den += __shfl_xor(den, off, 64);
#pragma unroll
        for (int j = 0; j < 8; ++j) acc[j] += __shfl_xor(acc[j], off, 64);
    }
    if (quad == 0) {
        float inv = 1.f / den;
        const float4* bv4 = reinterpret_cast<const float4*>(bias);
        float4 b0 = bv4[m16 * 2], b1 = bv4[m16 * 2 + 1];
        uint4 hw;
        hw.x = pk2(fmaxf(b0.x + acc[0] * inv, 0.f), fmaxf(b0.y + acc[1] * inv, 0.f));
        hw.y = pk2(fmaxf(b0.z + acc[2] * inv, 0.f), fmaxf(b0.w + acc[3] * inv, 0.f));
        hw.z = pk2(fmaxf(b1.x + acc[4] * inv, 0.f), fmaxf(b1.y + acc[5] * inv, 0.f));
        hw.w = pk2(fmaxf(b1.z + acc[6] * inv, 0.f), fmaxf(b1.w + acc[7] * inv, 0.f));
        *reinterpret_cast<uint4*>(o1 + (size_t)d * 128 + m16 * 8) = hw;
    }
}

// layer-2: 1 head x 128 ch; + b2, no ReLU; fp32 output.
__global__ __launch_bounds__(256) void agg2_kernel(const unsigned short* __restrict__ Hb,
                                                   const float* __restrict__ asrc,
                                                   const float* __restrict__ adst,
                                                   const int* __restrict__ rowptr,
                                                   const int* __restrict__ srcs,
                                                   const float* __restrict__ bias,
                                                   float* __restrict__ out, int n) {
    int wid = (blockIdx.x * 256 + threadIdx.x) >> 6;
    int lane = threadIdx.x & 63;
    if (wid >= n) return;
    int m16 = lane & 15, quad = lane >> 4;
    int d = wid;
    int beg = rowptr[d], end = rowptr[d + 1];
    float ad = adst[d];
    const uint4* H4 = reinterpret_cast<const uint4*>(Hb);
    float acc[8] = {};
    float den = 0.f;

    auto body = [&](int p, bool chk) {
        int ep = p + quad;
        bool valid = !chk || (ep < end);
        int se = srcs[valid ? ep : beg];
        float e = asrc[se] + ad;
        e = (e > 0.f) ? e : 0.2f * e;
        float pv = __expf(e);
        if (!valid) pv = 0.f;
        den += pv;
        uint4 hv = H4[(size_t)se * 16 + m16];
        float2 f0 = unpk(hv.x), f1 = unpk(hv.y), f2 = unpk(hv.z), f3 = unpk(hv.w);
        acc[0] += pv * f0.x; acc[1] += pv * f0.y;
        acc[2] += pv * f1.x; acc[3] += pv * f1.y;
        acc[4] += pv * f2.x; acc[5] += pv * f2.y;
        acc[6] += pv * f3.x; acc[7] += pv * f3.y;
    };
    int p = beg;
    for (; p + 8 <= end; p += 8) { body(p, false); body(p + 4, false); }
    for (; p < end; p += 4) body(p, true);

#pragma unroll
    for (int off = 16; off < 64; off <<= 1) {
        den += __shfl_xor(den, off, 64);
#pragma unroll
        for (int j = 0; j < 8; ++j) acc[j] += __shfl_xor(acc[j], off, 64);
    }
    float inv = 1.f / den;
    const float4* bv4 = reinterpret_cast<const float4*>(bias);
    float4 b0 = bv4[m16 * 2], b1 = bv4[m16 * 2 + 1];
    if (quad == 0) {
        float4 o;
        o.x = b0.x + acc[0] * inv; o.y = b0.y + acc[1] * inv;
        o.z = b0.z + acc[2] * inv; o.w = b0.w + acc[3] * inv;
        *reinterpret_cast<float4*>(out + (size_t)d * 128 + m16 * 8) = o;
    }
    if (quad == 1) {
        float4 o;
        o.x = b1.x + acc[4] * inv; o.y = b1.y + acc[5] * inv;
        o.z = b1.z + acc[6] * inv; o.w = b1.w + acc[7] * inv;
        *reinterpret_cast<float4*>(out + (size_t)d * 128 + m16 * 8 + 4) = o;
    }
}

// ---------------- launch ----------------

extern "C" void kernel_launch(void* const* d_in, const int* in_sizes, int n_in,
                              void* d_out, int out_size, void* d_ws, size_t ws_size,
                              hipStream_t stream) {
    const float* x   = (const float*)d_in[0];
    const int*   ei  = (const int*)d_in[1];
    const float* W1  = (const float*)d_in[2];
    const float* as1 = (const float*)d_in[3];
    const float* ad1 = (const float*)d_in[4];
    const float* b1  = (const float*)d_in[5];
    const float* W2  = (const float*)d_in[6];
    const float* as2 = (const float*)d_in[7];
    const float* ad2 = (const float*)d_in[8];
    const float* b2  = (const float*)d_in[9];

    int N = in_sizes[0] / 128;
    int E = in_sizes[1] / 2;
    int tot = E + N;
    int nb = (N + 255) / 256;           // scan blocks (<=256 required; N=50k -> 196)
    int nscat = (tot + SCAT_CH - 1) / SCAT_CH;

    char* wsb = (char*)d_ws;
    size_t off = 0;
    auto alloc = [&](size_t bytes) {
        void* p = wsb + off;
        off += (bytes + 255) & ~(size_t)255;
        return p;
    };
    unsigned short* A1  = (unsigned short*)alloc((size_t)N * 128 * 2); // out1 bf16 (agg1->gemm2)
    unsigned short* Hb  = (unsigned short*)alloc((size_t)N * 128 * 2); // h bf16 (h1 then h2)
    unsigned short* Bt1 = (unsigned short*)alloc(128 * 128 * 2);
    unsigned short* Bt2 = (unsigned short*)alloc(128 * 128 * 2);
    int*   counts = (int*)alloc((size_t)N * 4);
    int*   rowptr = (int*)alloc((size_t)(N + 1) * 4);
    int*   srcs   = (int*)alloc((size_t)tot * 4);
    int*   rank   = (int*)alloc((size_t)tot * 4);
    int*   bsum   = (int*)alloc(256 * 4);
    float* asrc1  = (float*)alloc((size_t)N * 4 * 4);
    float* adst1  = (float*)alloc((size_t)N * 4 * 4);
    float* asrc2  = (float*)alloc((size_t)N * 4);
    float* adst2  = (float*)alloc((size_t)N * 4);
    (void)ws_size; (void)n_in; (void)out_size;

    // CSR by dst (shared by both layers)
    hipMemsetAsync(counts, 0, (size_t)N * 4, stream);
    hist_rank<<<(tot + 255) / 256, 256, 0, stream>>>(ei, counts, rank, E, N);
    scan_partial<<<nb, 256, 0, stream>>>(counts, bsum, N);
    scan_bsums<<<1, 256, 0, stream>>>(bsum, nb);
    scan_final<<<nb, 256, 0, stream>>>(counts, bsum, rowptr, N, tot);
    scatter_part<<<nscat * 8, 256, 0, stream>>>(ei, rowptr, rank, srcs, E, N);

    // weight conversions (both in one launch)
    convWt2_kernel<<<128, 256, 0, stream>>>(W1, W2, Bt1, Bt2);

    int gblocks = (N + 63) / 64;

    // layer 1 (x split fused into GEMM; alpha1 fused into epilogue)
    gemm1_fused<<<gblocks, 256, 0, stream>>>(x, Bt1, Hb, as1, ad1, asrc1, adst1, N);
    agg1_kernel<<<(N + 3) / 4, 256, 0, stream>>>(Hb, asrc1, adst1, rowptr, srcs, b1, A1, N);

    // layer 2 (single-term bf16 A; alpha2 fused into epilogue)
    gemm2_fused<<<gblocks, 256, 0, stream>>>(A1, Bt2, Hb, as2, ad2, asrc2, adst2, N);
    agg2_kernel<<<(N + 3) / 4, 256, 0, stream>>>(Hb, asrc2, adst2, rowptr, srcs, b2,
                                                 (float*)d_out, N);
}